// Round 16
// baseline (1967.462 us; speedup 1.0000x reference)
//
#include <hip/hip_runtime.h>
#include <hip/hip_cooperative_groups.h>

namespace cg = cooperative_groups;

#define NT 20000
#define NC 100000
#define DT 512
#define DC 256
#define E_TC 100000
#define E_SIM 800000
#define E_TS 640000

#define KB_COL 0
#define KB_TAB (4 * NC)
#define NKEY   (4 * NC + 2 * NT)                 // 440000 joint cursor keys
#define NED_AB (3 * E_SIM + E_TC + E_TC + E_TS)  // 3240000 edges total
#define COLSTR 112                               // col arena: cs32|ns32|ds32|tc16
#define TABSTR 96                                // tab arena: rev24|ts72
#define NPASS  4                                 // fill windows
#define GFILL  2048                              // grid-stride fill blocks

typedef float f32x4 __attribute__((ext_vector_type(4)));
typedef __bf16 bf16x8 __attribute__((ext_vector_type(8)));

// ---------------- prep kernels ----------------

struct WD { const float* w0; const float* w1; const float* w2; const float* w3;
            __bf16* out; int K; int kshift; int ebase; };
struct WD8 { WD d[8]; };

__global__ void wprep_all(WD8 ds, int total) {
    int i = blockIdx.x * blockDim.x + threadIdx.x;
    if (i >= total) return;
#pragma unroll
    for (int s = 7; s >= 0; --s) {
        if (i >= ds.d[s].ebase) {
            const WD d = ds.d[s];
            const int idx = i - d.ebase;
            const int n = idx >> d.kshift;
            const int k = idx & (d.K - 1);
            float v = d.w0[(size_t)k * 128 + n];
            if (d.w1) v += d.w1[(size_t)k * 128 + n];
            if (d.w2) v += d.w2[(size_t)k * 128 + n];
            if (d.w3) v += d.w3[(size_t)k * 128 + n];
            d.out[(size_t)n * d.K + k] = (__bf16)v;
            return;
        }
    }
}

// sc[0]=qdot, sc[1]=c0, sc[2]=qn
__global__ void vecprep(const float* __restrict__ q, const float* __restrict__ Wq,
                        const float* __restrict__ bq,
                        const float* __restrict__ Wr2_rev, const float* __restrict__ Wr2_ts,
                        const float* __restrict__ Wl2_rev, const float* __restrict__ Wl2_ts,
                        const float* __restrict__ bl2_rev, const float* __restrict__ bl2_ts,
                        const float* __restrict__ Wlin,
                        const float* __restrict__ bl1_tc, const float* __restrict__ bl1_cs,
                        const float* __restrict__ bl1_ns, const float* __restrict__ bl1_ds,
                        const float* __restrict__ bl1_rev, const float* __restrict__ bl1_ts,
                        float* __restrict__ biasC, float* __restrict__ biasT1,
                        float* __restrict__ w2s, float* __restrict__ wrev,
                        float* __restrict__ wts, float* __restrict__ sc) {
    const int t = threadIdx.x;  // 0..127
    biasC[t] = bl1_tc[t] + bl1_cs[t] + bl1_ns[t] + bl1_ds[t];
    biasT1[t] = bl1_rev[t] + bl1_ts[t];
    float a = 0.f, b = 0.f, c = 0.f;
    for (int h = 0; h < 128; ++h) {
        const float wl = Wlin[h];
        a = fmaf(Wr2_rev[(size_t)t * 128 + h] + Wr2_ts[(size_t)t * 128 + h], wl, a);
        b = fmaf(Wl2_rev[(size_t)t * 128 + h], wl, b);
        c = fmaf(Wl2_ts[(size_t)t * 128 + h], wl, c);
    }
    w2s[t] = a; wrev[t] = b; wts[t] = c;
    float qv = bq[t];
    for (int k = 0; k < 512; ++k) qv = fmaf(q[k], Wq[(size_t)k * 128 + t], qv);
    __shared__ float sh[128];
    sh[t] = qv * Wlin[t];
    __syncthreads();
    for (int st = 64; st >= 1; st >>= 1) { if (t < st) sh[t] += sh[t + st]; __syncthreads(); }
    if (t == 0) sc[0] = sh[0];
    __syncthreads();
    sh[t] = (bl2_rev[t] + bl2_ts[t]) * Wlin[t];
    __syncthreads();
    for (int st = 64; st >= 1; st >>= 1) { if (t < st) sh[t] += sh[t + st]; __syncthreads(); }
    if (t == 0) sc[1] = sh[0];
    __syncthreads();
    float ss = 0.f;
    for (int k = t; k < 512; k += 128) { const float v = q[k]; ss = fmaf(v, v, ss); }
    sh[t] = ss;
    __syncthreads();
    for (int st = 64; st >= 1; st >>= 1) { if (t < st) sh[t] += sh[t + st]; __syncthreads(); }
    if (t == 0) sc[2] = fmaxf(sqrtf(sh[0]), 1e-12f);
}

// ---------------- A-resident multi-output MFMA GEMMs (round-13-verified) ----------------

struct B5 { const __bf16* p[5]; };
struct Y5 { __bf16* p[5]; };

__launch_bounds__(256, 2)
__global__ void gemm_col5(const float* __restrict__ X, B5 wp, const float* __restrict__ bias,
                          Y5 yp, int M) {
    __shared__ __bf16 Bs[128 * 256];   // 64 KB
    const int t = threadIdx.x;
    const int lane = t & 63;
    const int wave = t >> 6;
    const int l15 = lane & 15;
    const int kg = lane >> 4;
    const int rowbase = blockIdx.x * 128 + wave * 32;

    bf16x8 af[2][8];
#pragma unroll
    for (int m = 0; m < 2; ++m) {
        int r = rowbase + m * 16 + l15;
        r = (r < M) ? r : (M - 1);
        const float* baseA = X + (size_t)r * 256 + kg * 8;
#pragma unroll
        for (int ks = 0; ks < 8; ++ks) {
            const float4 x0 = *reinterpret_cast<const float4*>(baseA + ks * 32);
            const float4 x1 = *reinterpret_cast<const float4*>(baseA + ks * 32 + 4);
            bf16x8 tt;
            tt[0] = (__bf16)x0.x; tt[1] = (__bf16)x0.y; tt[2] = (__bf16)x0.z; tt[3] = (__bf16)x0.w;
            tt[4] = (__bf16)x1.x; tt[5] = (__bf16)x1.y; tt[6] = (__bf16)x1.z; tt[7] = (__bf16)x1.w;
            af[m][ks] = tt;
        }
    }

#pragma unroll
    for (int o = 0; o < 5; ++o) {
        __syncthreads();
        const __bf16* Wt = wp.p[o];
#pragma unroll
        for (int i = 0; i < 16; ++i) {
            const int u = t + i * 256;
            const int row = u >> 5;
            const int ku = u & 31;
            const bf16x8 v = *reinterpret_cast<const bf16x8*>(Wt + (size_t)row * 256 + ku * 8);
            *reinterpret_cast<bf16x8*>(&Bs[row * 256 + ((ku ^ (row & 7)) << 3)]) = v;
        }
        __syncthreads();
        f32x4 acc[2][8];
#pragma unroll
        for (int m = 0; m < 2; ++m)
#pragma unroll
            for (int n = 0; n < 8; ++n) acc[m][n] = (f32x4)0.f;
#pragma unroll
        for (int ks = 0; ks < 8; ++ks) {
            const int ku = ks * 4 + kg;
#pragma unroll
            for (int n = 0; n < 8; ++n) {
                const int r = n * 16 + l15;
                const bf16x8 bf = *reinterpret_cast<const bf16x8*>(&Bs[r * 256 + ((ku ^ (r & 7)) << 3)]);
                acc[0][n] = __builtin_amdgcn_mfma_f32_16x16x32_bf16(af[0][ks], bf, acc[0][n], 0, 0, 0);
                acc[1][n] = __builtin_amdgcn_mfma_f32_16x16x32_bf16(af[1][ks], bf, acc[1][n], 0, 0, 0);
            }
        }
        __bf16* Y = yp.p[o];
#pragma unroll
        for (int n = 0; n < 8; ++n) {
            const int col = n * 16 + l15;
            const float bv = (o == 0) ? bias[col] : 0.f;
#pragma unroll
            for (int m = 0; m < 2; ++m)
#pragma unroll
                for (int rr = 0; rr < 4; ++rr) {
                    const int row = rowbase + m * 16 + kg * 4 + rr;
                    if (row < M) Y[(size_t)row * 128 + col] = (__bf16)(acc[m][n][rr] + bv);
                }
        }
    }
}

struct B3 { const __bf16* p[3]; };
struct Y3 { __bf16* p[3]; };

__launch_bounds__(256, 2)
__global__ void gemm_tab3(const float* __restrict__ X, B3 wp, const float* __restrict__ bias,
                          Y3 yp, const float* __restrict__ q, const float* __restrict__ sc,
                          float* __restrict__ wgt, int M) {
    __shared__ __bf16 Bs[128 * 256];   // 64 KB (half-K chunk)
    const int t = threadIdx.x;
    const int lane = t & 63;
    const int wave = t >> 6;
    const int l15 = lane & 15;
    const int kg = lane >> 4;
    const int rowbase = blockIdx.x * 64 + wave * 16;
    const int r0 = rowbase + l15;
    const bool rv = r0 < M;
    const int rc = rv ? r0 : (M - 1);
    const float* baseA = X + (size_t)rc * 512 + kg * 8;

    bf16x8 af[16];
    float dot = 0.f, ss = 0.f;
#pragma unroll
    for (int ks = 0; ks < 16; ++ks) {
        const float4 x0 = *reinterpret_cast<const float4*>(baseA + ks * 32);
        const float4 x1 = *reinterpret_cast<const float4*>(baseA + ks * 32 + 4);
        const float4 q0 = *reinterpret_cast<const float4*>(q + kg * 8 + ks * 32);
        const float4 q1 = *reinterpret_cast<const float4*>(q + kg * 8 + ks * 32 + 4);
        dot += x0.x * q0.x + x0.y * q0.y + x0.z * q0.z + x0.w * q0.w
             + x1.x * q1.x + x1.y * q1.y + x1.z * q1.z + x1.w * q1.w;
        ss += x0.x * x0.x + x0.y * x0.y + x0.z * x0.z + x0.w * x0.w
            + x1.x * x1.x + x1.y * x1.y + x1.z * x1.z + x1.w * x1.w;
        bf16x8 tt;
        tt[0] = (__bf16)x0.x; tt[1] = (__bf16)x0.y; tt[2] = (__bf16)x0.z; tt[3] = (__bf16)x0.w;
        tt[4] = (__bf16)x1.x; tt[5] = (__bf16)x1.y; tt[6] = (__bf16)x1.z; tt[7] = (__bf16)x1.w;
        af[ks] = tt;
    }
    dot += __shfl_xor(dot, 16); dot += __shfl_xor(dot, 32);
    ss  += __shfl_xor(ss, 16);  ss  += __shfl_xor(ss, 32);
    if (lane < 16 && rv) {
        const float nx = fmaxf(sqrtf(ss), 1e-12f);
        wgt[r0] = fmaxf(dot, 0.f) / (nx * sc[2]);
    }

#pragma unroll
    for (int o = 0; o < 3; ++o) {
        f32x4 acc[8];
#pragma unroll
        for (int n = 0; n < 8; ++n) acc[n] = (f32x4)0.f;
        const __bf16* Wt = wp.p[o];
#pragma unroll
        for (int c = 0; c < 2; ++c) {
            __syncthreads();
#pragma unroll
            for (int i = 0; i < 16; ++i) {
                const int u = t + i * 256;
                const int row = u >> 5;
                const int ku = u & 31;
                const bf16x8 v = *reinterpret_cast<const bf16x8*>(Wt + (size_t)row * 512 + c * 256 + ku * 8);
                *reinterpret_cast<bf16x8*>(&Bs[row * 256 + ((ku ^ (row & 7)) << 3)]) = v;
            }
            __syncthreads();
#pragma unroll
            for (int ks = 0; ks < 8; ++ks) {
                const int ku = ks * 4 + kg;
#pragma unroll
                for (int n = 0; n < 8; ++n) {
                    const int r = n * 16 + l15;
                    const bf16x8 bf = *reinterpret_cast<const bf16x8*>(&Bs[r * 256 + ((ku ^ (r & 7)) << 3)]);
                    acc[n] = __builtin_amdgcn_mfma_f32_16x16x32_bf16(af[c * 8 + ks], bf, acc[n], 0, 0, 0);
                }
            }
        }
        __bf16* Y = yp.p[o];
#pragma unroll
        for (int n = 0; n < 8; ++n) {
            const int col = n * 16 + l15;
            const float bv = (o == 0) ? bias[col] : 0.f;
#pragma unroll
            for (int rr = 0; rr < 4; ++rr) {
                const int row = rowbase + kg * 4 + rr;
                if (row < M) Y[(size_t)row * 128 + col] = (__bf16)(acc[n][rr] + bv);
            }
        }
    }
}

// ---------------- capacity-padded CSR (count-free, windowed grid-stride fill) ----------------
// Col arena: per dst 112 slots = cs[0,32) ns[32,64) ds[64,96) tc[96,112).
// Tab arena (int2): per dst 96 slots = rev[0,24){src,0} | ts[24,96){NC+src, raw ew}.
// APPNP norm baked later (tail_coop) — no deg atomics here.

struct ED { const int* dst; const int* src; int E; int ebase; int ng; int g;
            int keybase; int srcoff; int ts; };
struct ED6 { ED d[6]; };

__global__ void fill_win(ED6 ds, const float* __restrict__ ew_ts, int* __restrict__ cur,
                         int* __restrict__ ed_idx, int2* __restrict__ edT,
                         int lo, int hi, int total) {
    for (int e = blockIdx.x * blockDim.x + threadIdx.x; e < total;
         e += gridDim.x * blockDim.x) {
#pragma unroll
        for (int i = 5; i >= 0; --i) {
            if (e >= ds.d[i].ebase) {
                const ED d = ds.d[i];
                const int le = e - d.ebase;
                const int dstv = d.dst[le];
                const int key = d.keybase + dstv * d.ng + d.g;
                if (key >= lo && key < hi) {
                    const int srcv = d.src[le];
                    const int slot = atomicAdd(&cur[key], 1);
                    if (key < KB_TAB) {
                        const int g = key & 3;
                        const int cap = (g < 3) ? 32 : 16;
                        if (slot < cap)
                            ed_idx[(key >> 2) * COLSTR + g * 32 + slot] = d.srcoff + srcv;
                    } else {
                        const int k2 = key - KB_TAB;
                        if (k2 & 1) {                      // ts edge: store raw ew
                            if (slot < 72)
                                edT[(k2 >> 1) * TABSTR + 24 + slot] =
                                    make_int2(NC + srcv, __float_as_int(ew_ts[le]));
                        } else {                           // rev edge
                            if (slot < 24)
                                edT[(k2 >> 1) * TABSTR + slot] = make_int2(srcv, 0);
                        }
                    }
                }
                break;
            }
        }
    }
}

// ---------------- fused row kernels (padded-arena indexing) ----------------

__launch_bounds__(256)
__global__ void col_fused(const __bf16* __restrict__ selfRow, const __bf16* __restrict__ featCat,
                          const int* __restrict__ cur, const int* __restrict__ ed_idx,
                          const float* __restrict__ wvec, float* __restrict__ outv, int n) {
    const int wave = threadIdx.x >> 6;
    const int lane = threadIdx.x & 63;
    const int sg = lane >> 4;
    const int sl = lane & 15;
    const int row = blockIdx.x * 4 + wave;
    if (row >= n) return;
    const int4 l4 = *reinterpret_cast<const int4*>(&cur[row * 4]);
    int len[4];
    len[0] = (l4.x < 32) ? l4.x : 32;
    len[1] = (l4.y < 32) ? l4.y : 32;
    len[2] = (l4.z < 32) ? l4.z : 32;
    len[3] = (l4.w < 16) ? l4.w : 16;
    const int rowbase = row * COLSTR;
    float s8[8] = {0.f, 0.f, 0.f, 0.f, 0.f, 0.f, 0.f, 0.f};
#pragma unroll
    for (int g = 0; g < 4; ++g) {
        const int lg = len[g];
        if (lg <= 0) continue;
        const int base = rowbase + g * 32;
        const float w = 1.0f / (float)lg;
        int j = sg;
        for (; j + 4 < lg; j += 8) {
            const int s0 = ed_idx[base + j];
            const int s1 = ed_idx[base + j + 4];
            const bf16x8 v0 = *reinterpret_cast<const bf16x8*>(&featCat[(size_t)s0 * 128 + sl * 8]);
            const bf16x8 v1 = *reinterpret_cast<const bf16x8*>(&featCat[(size_t)s1 * 128 + sl * 8]);
#pragma unroll
            for (int t = 0; t < 8; ++t) {
                s8[t] = fmaf(w, (float)v0[t], s8[t]);
                s8[t] = fmaf(w, (float)v1[t], s8[t]);
            }
        }
        if (j < lg) {
            const int s0 = ed_idx[base + j];
            const bf16x8 v0 = *reinterpret_cast<const bf16x8*>(&featCat[(size_t)s0 * 128 + sl * 8]);
#pragma unroll
            for (int t = 0; t < 8; ++t) s8[t] = fmaf(w, (float)v0[t], s8[t]);
        }
    }
#pragma unroll
    for (int t = 0; t < 8; ++t) {
        s8[t] += __shfl_xor(s8[t], 16);
        s8[t] += __shfl_xor(s8[t], 32);
    }
    const bf16x8 gv = *reinterpret_cast<const bf16x8*>(&selfRow[(size_t)row * 128 + sl * 8]);
    const float4 w0 = *reinterpret_cast<const float4*>(&wvec[sl * 8]);
    const float4 w1 = *reinterpret_cast<const float4*>(&wvec[sl * 8 + 4]);
    const float ww[8] = {w0.x, w0.y, w0.z, w0.w, w1.x, w1.y, w1.z, w1.w};
    float d = 0.f;
#pragma unroll
    for (int t = 0; t < 8; ++t) d = fmaf(fmaxf(s8[t] + (float)gv[t], 0.f), ww[t], d);
#pragma unroll
    for (int off = 8; off; off >>= 1) d += __shfl_xor(d, off);
    if (lane == 0) outv[row] = d;
}

__launch_bounds__(256)
__global__ void tab_fused(const __bf16* __restrict__ selfRow, const __bf16* __restrict__ featCat,
                          const int* __restrict__ cur, const int2* __restrict__ edT,
                          const float* __restrict__ wa, const float* __restrict__ wb,
                          float* __restrict__ ya, float* __restrict__ yb, int n) {
    const int wave = threadIdx.x >> 6;
    const int lane = threadIdx.x & 63;
    const int sg = lane >> 4;
    const int sl = lane & 15;
    const int row = blockIdx.x * 4 + wave;
    if (row >= n) return;
    const int2 l2 = *reinterpret_cast<const int2*>(&cur[KB_TAB + row * 2]);
    int len[2];
    len[0] = (l2.x < 24) ? l2.x : 24;
    len[1] = (l2.y < 72) ? l2.y : 72;
    const int rowbase = row * TABSTR;
    float s8[8] = {0.f, 0.f, 0.f, 0.f, 0.f, 0.f, 0.f, 0.f};
#pragma unroll
    for (int g = 0; g < 2; ++g) {
        const int lg = len[g];
        if (lg <= 0) continue;
        const int base = rowbase + g * 24;
        const float w = 1.0f / (float)lg;
        int j = sg;
        for (; j + 4 < lg; j += 8) {
            const int s0 = edT[base + j].x;
            const int s1 = edT[base + j + 4].x;
            const bf16x8 v0 = *reinterpret_cast<const bf16x8*>(&featCat[(size_t)s0 * 128 + sl * 8]);
            const bf16x8 v1 = *reinterpret_cast<const bf16x8*>(&featCat[(size_t)s1 * 128 + sl * 8]);
#pragma unroll
            for (int t = 0; t < 8; ++t) {
                s8[t] = fmaf(w, (float)v0[t], s8[t]);
                s8[t] = fmaf(w, (float)v1[t], s8[t]);
            }
        }
        if (j < lg) {
            const int s0 = edT[base + j].x;
            const bf16x8 v0 = *reinterpret_cast<const bf16x8*>(&featCat[(size_t)s0 * 128 + sl * 8]);
#pragma unroll
            for (int t = 0; t < 8; ++t) s8[t] = fmaf(w, (float)v0[t], s8[t]);
        }
    }
#pragma unroll
    for (int t = 0; t < 8; ++t) {
        s8[t] += __shfl_xor(s8[t], 16);
        s8[t] += __shfl_xor(s8[t], 32);
    }
    const bf16x8 gv = *reinterpret_cast<const bf16x8*>(&selfRow[(size_t)row * 128 + sl * 8]);
    const float4 a0 = *reinterpret_cast<const float4*>(&wa[sl * 8]);
    const float4 a1 = *reinterpret_cast<const float4*>(&wa[sl * 8 + 4]);
    const float4 b0 = *reinterpret_cast<const float4*>(&wb[sl * 8]);
    const float4 b1 = *reinterpret_cast<const float4*>(&wb[sl * 8 + 4]);
    const float wwa[8] = {a0.x, a0.y, a0.z, a0.w, a1.x, a1.y, a1.z, a1.w};
    const float wwb[8] = {b0.x, b0.y, b0.z, b0.w, b1.x, b1.y, b1.z, b1.w};
    float da = 0.f, db = 0.f;
#pragma unroll
    for (int t = 0; t < 8; ++t) {
        const float rv = fmaxf(s8[t] + (float)gv[t], 0.f);
        da = fmaf(rv, wwa[t], da);
        db = fmaf(rv, wwb[t], db);
    }
#pragma unroll
    for (int off = 8; off; off >>= 1) { da += __shfl_xor(da, off); db += __shfl_xor(db, off); }
    if (lane == 0) { ya[row] = da; yb[row] = db; }
}

// ---------------- cooperative tail: deg/dis -> nrm -> y0 -> 10x APPNP -> out ----------------

__launch_bounds__(256)
__global__ void tail_coop(const int* __restrict__ cur, int2* __restrict__ edT,
                          const float* __restrict__ tvs, const float* __restrict__ val2,
                          const float* __restrict__ wgt, const float* __restrict__ sc,
                          const float* __restrict__ blin, float* __restrict__ dis,
                          float* __restrict__ y0, float* __restrict__ za,
                          float* __restrict__ zb, float* __restrict__ out) {
    cg::grid_group grid = cg::this_grid();
    const int row = blockIdx.x * 16 + (threadIdx.x >> 4);
    const int l = threadIdx.x & 15;
    const bool ok = row < NT;
    int lenR = 0, lenT = 0, baseR = 0, baseT = 0;
    if (ok) {
        const int2 l2 = *reinterpret_cast<const int2*>(&cur[KB_TAB + row * 2]);
        lenR = (l2.x < 24) ? l2.x : 24;
        lenT = (l2.y < 72) ? l2.y : 72;
        baseR = row * TABSTR;
        baseT = row * TABSTR + 24;
    }
    // phase 1: weighted ts degree (+self-loop 1) -> dis; and y0
    if (ok) {
        float sdeg = 0.f, sy = 0.f;
        const float wR = (lenR > 0) ? 1.0f / (float)lenR : 0.f;
        for (int j = l; j < lenR; j += 16) sy = fmaf(wR, val2[edT[baseR + j].x], sy);
        const float wT = (lenT > 0) ? 1.0f / (float)lenT : 0.f;
        for (int j = l; j < lenT; j += 16) {
            const int2 p = edT[baseT + j];
            sdeg += __int_as_float(p.y);
            sy = fmaf(wT, val2[p.x], sy);
        }
#pragma unroll
        for (int off = 8; off; off >>= 1) {
            sdeg += __shfl_xor(sdeg, off);
            sy += __shfl_xor(sy, off);
        }
        if (l == 0) {
            const float dg = sdeg + 1.0f;
            dis[row] = (dg > 0.f) ? (1.0f / sqrtf(dg)) : 0.f;
            y0[row] = tvs[row] + sc[1] + wgt[row] * sc[0] + sy;
        }
    }
    grid.sync();
    // phase 2: bake nrm = dis[src]*ew*dis[dst] into ts slots
    if (ok) {
        const float dr = dis[row];
        for (int j = l; j < lenT; j += 16) {
            const int2 p = edT[baseT + j];
            const float nv = dis[p.x - NC] * __int_as_float(p.y) * dr;
            edT[baseT + j].y = __float_as_int(nv);
        }
    }
    grid.sync();
    // phases 3..12: APPNP
    const float* zin = y0;
    float* zo = za;
    for (int it = 0; it < 10; ++it) {
        if (ok) {
            float s = 0.f;
            int j = l;
            for (; j + 16 < lenT; j += 32) {
                const int2 p0 = edT[baseT + j];
                const int2 p1 = edT[baseT + j + 16];
                s = fmaf(__int_as_float(p0.y), zin[p0.x - NC], s);
                s = fmaf(__int_as_float(p1.y), zin[p1.x - NC], s);
            }
            if (j < lenT) {
                const int2 p0 = edT[baseT + j];
                s = fmaf(__int_as_float(p0.y), zin[p0.x - NC], s);
            }
#pragma unroll
            for (int off = 8; off; off >>= 1) s += __shfl_xor(s, off);
            if (l == 0) {
                const float d = dis[row];
                const float v = 0.8f * (s + d * d * zin[row]) + 0.2f * y0[row];
                if (it == 9) out[row] = v + blin[0];
                else zo[row] = v;
            }
        }
        grid.sync();
        zin = zo;
        zo = (zo == za) ? zb : za;
    }
}

// ---------------- host ----------------

extern "C" void kernel_launch(void* const* d_in, const int* in_sizes, int n_in,
                              void* d_out, int out_size, void* d_ws, size_t ws_size,
                              hipStream_t stream) {
    const float* table_x  = (const float*)d_in[0];
    const float* column_x = (const float*)d_in[1];
    const float* q        = (const float*)d_in[2];
    const float* Wl1_tc  = (const float*)d_in[3];  const float* bl1_tc  = (const float*)d_in[4];  const float* Wr1_tc  = (const float*)d_in[5];
    const float* Wl1_rev = (const float*)d_in[6];  const float* bl1_rev = (const float*)d_in[7];  const float* Wr1_rev = (const float*)d_in[8];
    const float* Wl1_cs  = (const float*)d_in[9];  const float* bl1_cs  = (const float*)d_in[10]; const float* Wr1_cs  = (const float*)d_in[11];
    const float* Wl1_ns  = (const float*)d_in[12]; const float* bl1_ns  = (const float*)d_in[13]; const float* Wr1_ns  = (const float*)d_in[14];
    const float* Wl1_ds  = (const float*)d_in[15]; const float* bl1_ds  = (const float*)d_in[16]; const float* Wr1_ds  = (const float*)d_in[17];
    const float* Wl1_ts  = (const float*)d_in[18]; const float* bl1_ts  = (const float*)d_in[19]; const float* Wr1_ts  = (const float*)d_in[20];
    const float* Wl2_rev = (const float*)d_in[21]; const float* bl2_rev = (const float*)d_in[22]; const float* Wr2_rev = (const float*)d_in[23];
    const float* Wl2_ts  = (const float*)d_in[24]; const float* bl2_ts  = (const float*)d_in[25]; const float* Wr2_ts  = (const float*)d_in[26];
    const float* Wq   = (const float*)d_in[27]; const float* bq   = (const float*)d_in[28];
    const float* Wlin = (const float*)d_in[29]; const float* blin = (const float*)d_in[30];
    const float* ts_ew = (const float*)d_in[31];
    const int* tc_src = (const int*)d_in[32];
    const int* tc_dst = (const int*)d_in[33];
    const int* cs_ei  = (const int*)d_in[34];
    const int* ns_ei  = (const int*)d_in[35];
    const int* ds_ei  = (const int*)d_in[36];
    const int* ts_ei  = (const int*)d_in[37];

    // ---- workspace carve ----
    char* w = (char*)d_ws;
    size_t off = 0;
    auto alloc = [&](size_t bytes) -> void* {
        void* p = w + off;
        off += (bytes + 255) & ~(size_t)255;
        return p;
    };
    __bf16* featC = (__bf16*)alloc(((size_t)3 * NC + NT) * 128 * 2);  // cs | ns | ds | tc
    __bf16* featT = (__bf16*)alloc(((size_t)NC + NT) * 128 * 2);      // rev | ts
    __bf16* projC_cs  = featC;
    __bf16* projC_ns  = featC + (size_t)NC * 128;
    __bf16* projC_ds  = featC + (size_t)2 * NC * 128;
    __bf16* projT_tc  = featC + (size_t)3 * NC * 128;
    __bf16* projC_rev = featT;
    __bf16* projT_ts  = featT + (size_t)NC * 128;
    __bf16* gemmC = (__bf16*)alloc((size_t)NC * 128 * 2);
    __bf16* gemmT = (__bf16*)alloc((size_t)NT * 128 * 2);
    float* val2  = (float*)alloc((size_t)(NC + NT) * 4);   // colv | tvt
    float* f_colv = val2;
    float* f_tvt  = val2 + NC;
    float* f_tvs = (float*)alloc((size_t)NT * 4);
    float* f_wgt = (float*)alloc((size_t)NT * 4);
    float* f_dis = (float*)alloc((size_t)NT * 4);
    float* f_y0  = (float*)alloc((size_t)NT * 4);
    float* f_za  = (float*)alloc((size_t)NT * 4);
    float* f_zb  = (float*)alloc((size_t)NT * 4);
    __bf16* WtS1c  = (__bf16*)alloc((size_t)128 * 256 * 2);
    __bf16* Wt_cs  = (__bf16*)alloc((size_t)128 * 256 * 2);
    __bf16* Wt_ns  = (__bf16*)alloc((size_t)128 * 256 * 2);
    __bf16* Wt_ds  = (__bf16*)alloc((size_t)128 * 256 * 2);
    __bf16* Wt_rev = (__bf16*)alloc((size_t)128 * 256 * 2);
    __bf16* Wt_tc  = (__bf16*)alloc((size_t)128 * 512 * 2);
    __bf16* WtS1t  = (__bf16*)alloc((size_t)128 * 512 * 2);
    __bf16* Wt_ts  = (__bf16*)alloc((size_t)128 * 512 * 2);
    float* f_biasC  = (float*)alloc(128 * 4);
    float* f_biasT1 = (float*)alloc(128 * 4);
    float* f_w2s  = (float*)alloc(128 * 4);
    float* f_wrev = (float*)alloc(128 * 4);
    float* f_wts  = (float*)alloc(128 * 4);
    float* f_sc   = (float*)alloc(16 * 4);
    int* i_cur  = (int*)alloc((size_t)NKEY * 4);
    int* ed_idx = (int*)alloc((size_t)NC * COLSTR * 4);    // padded col arena
    int2* edT   = (int2*)alloc((size_t)NT * TABSTR * 8);   // padded tab arena
    if (off > ws_size) return;

    auto cdiv = [](int a, int b) { return (a + b - 1) / b; };

    // ---- weight/vector prep (2 dispatches) ----
    {
        WD8 ds;
        int eb = 0;
        auto set = [&](int i, const float* a, const float* b2, const float* c, const float* d2,
                       __bf16* o, int K, int ksh) {
            ds.d[i] = {a, b2, c, d2, o, K, ksh, eb};
            eb += 128 * K;
        };
        set(0, Wr1_tc, Wr1_cs, Wr1_ns, Wr1_ds, WtS1c, 256, 8);
        set(1, Wl1_cs, nullptr, nullptr, nullptr, Wt_cs, 256, 8);
        set(2, Wl1_ns, nullptr, nullptr, nullptr, Wt_ns, 256, 8);
        set(3, Wl1_ds, nullptr, nullptr, nullptr, Wt_ds, 256, 8);
        set(4, Wl1_rev, nullptr, nullptr, nullptr, Wt_rev, 256, 8);
        set(5, Wl1_tc, nullptr, nullptr, nullptr, Wt_tc, 512, 9);
        set(6, Wr1_rev, Wr1_ts, nullptr, nullptr, WtS1t, 512, 9);
        set(7, Wl1_ts, nullptr, nullptr, nullptr, Wt_ts, 512, 9);
        wprep_all<<<cdiv(eb, 256), 256, 0, stream>>>(ds, eb);
    }
    vecprep<<<1, 128, 0, stream>>>(q, Wq, bq, Wr2_rev, Wr2_ts, Wl2_rev, Wl2_ts,
                                   bl2_rev, bl2_ts, Wlin, bl1_tc, bl1_cs, bl1_ns, bl1_ds,
                                   bl1_rev, bl1_ts, f_biasC, f_biasT1,
                                   f_w2s, f_wrev, f_wts, f_sc);

    // ---- GEMMs: A-resident, X read once per side ----
    {
        B5 wp; wp.p[0] = WtS1c; wp.p[1] = Wt_cs; wp.p[2] = Wt_ns; wp.p[3] = Wt_ds; wp.p[4] = Wt_rev;
        Y5 yp; yp.p[0] = gemmC; yp.p[1] = projC_cs; yp.p[2] = projC_ns; yp.p[3] = projC_ds; yp.p[4] = projC_rev;
        gemm_col5<<<cdiv(NC, 128), 256, 0, stream>>>(column_x, wp, f_biasC, yp, NC);
    }
    {
        B3 wp; wp.p[0] = WtS1t; wp.p[1] = Wt_tc; wp.p[2] = Wt_ts;
        Y3 yp; yp.p[0] = gemmT; yp.p[1] = projT_tc; yp.p[2] = projT_ts;
        gemm_tab3<<<cdiv(NT, 64), 256, 0, stream>>>(table_x, wp, f_biasT1, yp, q, f_sc, f_wgt, NT);
    }

    // ---- count-free padded CSR: windowed grid-stride fills (no deg atomics) ----
    ED6 cds;
    cds.d[0] = {cs_ei + E_SIM, cs_ei, E_SIM, 0,                  4, 0, KB_COL, 0,      0};
    cds.d[1] = {ns_ei + E_SIM, ns_ei, E_SIM, E_SIM,              4, 1, KB_COL, NC,     0};
    cds.d[2] = {ds_ei + E_SIM, ds_ei, E_SIM, 2 * E_SIM,          4, 2, KB_COL, 2 * NC, 0};
    cds.d[3] = {tc_dst, tc_src, E_TC, 3 * E_SIM,                 4, 3, KB_COL, 3 * NC, 0};
    cds.d[4] = {tc_src, tc_dst, E_TC, 3 * E_SIM + E_TC,          2, 0, KB_TAB, 0,      0};
    cds.d[5] = {ts_ei + E_TS, ts_ei, E_TS, 3 * E_SIM + 2 * E_TC, 2, 1, KB_TAB, NC,     1};

    hipMemsetAsync(i_cur, 0, (size_t)NKEY * 4, stream);
    for (int p = 0; p < NPASS; ++p) {
        const int lo = (int)((long long)NKEY * p / NPASS);
        const int hi = (int)((long long)NKEY * (p + 1) / NPASS);
        fill_win<<<GFILL, 256, 0, stream>>>(cds, ts_ew, i_cur, ed_idx, edT, lo, hi, NED_AB);
    }

    // ---- fused aggregation + relu + dot ----
    col_fused<<<cdiv(NC, 4), 256, 0, stream>>>(gemmC, featC, i_cur, ed_idx,
                                               f_wrev, f_colv, NC);
    tab_fused<<<cdiv(NT, 4), 256, 0, stream>>>(gemmT, featT, i_cur, edT,
                                               f_w2s, f_wts, f_tvs, f_tvt, NT);

    // ---- cooperative tail: deg/dis -> nrm -> y0 -> 10x APPNP -> out ----
    {
        float* outp = (float*)d_out;
        void* args[] = {(void*)&i_cur, (void*)&edT, (void*)&f_tvs, (void*)&val2,
                        (void*)&f_wgt, (void*)&f_sc, (void*)&blin, (void*)&f_dis,
                        (void*)&f_y0, (void*)&f_za, (void*)&f_zb, (void*)&outp};
        hipLaunchCooperativeKernel((void*)tail_coop, dim3(cdiv(NT, 16)), dim3(256),
                                   args, 0, stream);
    }
}

// Round 17
// 552.379 us; speedup vs baseline: 3.5618x; 3.5618x over previous
//
#include <hip/hip_runtime.h>

#define NT 20000
#define NC 100000
#define DT 512
#define DC 256
#define E_TC 100000
#define E_SIM 800000
#define E_TS 640000

#define KB_COL 0
#define KB_TAB (4 * NC)
#define NKEY   (4 * NC + 2 * NT)                 // 440000 joint cursor keys
#define NED_AB (3 * E_SIM + E_TC + E_TC + E_TS)  // 3240000 edges total
#define COLSTR 112                               // col arena: cs32|ns32|ds32|tc16
#define TABSTR 96                                // tab arena: rev24|ts72
#define NPASS  4                                 // fill windows
#define GFILL  2048                              // grid-stride fill blocks

typedef float f32x4 __attribute__((ext_vector_type(4)));
typedef __bf16 bf16x8 __attribute__((ext_vector_type(8)));

// ---------------- prep kernels ----------------

struct WD { const float* w0; const float* w1; const float* w2; const float* w3;
            __bf16* out; int K; int kshift; int ebase; };
struct WD8 { WD d[8]; };

__global__ void wprep_all(WD8 ds, int total) {
    int i = blockIdx.x * blockDim.x + threadIdx.x;
    if (i >= total) return;
#pragma unroll
    for (int s = 7; s >= 0; --s) {
        if (i >= ds.d[s].ebase) {
            const WD d = ds.d[s];
            const int idx = i - d.ebase;
            const int n = idx >> d.kshift;
            const int k = idx & (d.K - 1);
            float v = d.w0[(size_t)k * 128 + n];
            if (d.w1) v += d.w1[(size_t)k * 128 + n];
            if (d.w2) v += d.w2[(size_t)k * 128 + n];
            if (d.w3) v += d.w3[(size_t)k * 128 + n];
            d.out[(size_t)n * d.K + k] = (__bf16)v;
            return;
        }
    }
}

// sc[0]=qdot, sc[1]=c0, sc[2]=qn
__global__ void vecprep(const float* __restrict__ q, const float* __restrict__ Wq,
                        const float* __restrict__ bq,
                        const float* __restrict__ Wr2_rev, const float* __restrict__ Wr2_ts,
                        const float* __restrict__ Wl2_rev, const float* __restrict__ Wl2_ts,
                        const float* __restrict__ bl2_rev, const float* __restrict__ bl2_ts,
                        const float* __restrict__ Wlin,
                        const float* __restrict__ bl1_tc, const float* __restrict__ bl1_cs,
                        const float* __restrict__ bl1_ns, const float* __restrict__ bl1_ds,
                        const float* __restrict__ bl1_rev, const float* __restrict__ bl1_ts,
                        float* __restrict__ biasC, float* __restrict__ biasT1,
                        float* __restrict__ w2s, float* __restrict__ wrev,
                        float* __restrict__ wts, float* __restrict__ sc) {
    const int t = threadIdx.x;  // 0..127
    biasC[t] = bl1_tc[t] + bl1_cs[t] + bl1_ns[t] + bl1_ds[t];
    biasT1[t] = bl1_rev[t] + bl1_ts[t];
    float a = 0.f, b = 0.f, c = 0.f;
    for (int h = 0; h < 128; ++h) {
        const float wl = Wlin[h];
        a = fmaf(Wr2_rev[(size_t)t * 128 + h] + Wr2_ts[(size_t)t * 128 + h], wl, a);
        b = fmaf(Wl2_rev[(size_t)t * 128 + h], wl, b);
        c = fmaf(Wl2_ts[(size_t)t * 128 + h], wl, c);
    }
    w2s[t] = a; wrev[t] = b; wts[t] = c;
    float qv = bq[t];
    for (int k = 0; k < 512; ++k) qv = fmaf(q[k], Wq[(size_t)k * 128 + t], qv);
    __shared__ float sh[128];
    sh[t] = qv * Wlin[t];
    __syncthreads();
    for (int st = 64; st >= 1; st >>= 1) { if (t < st) sh[t] += sh[t + st]; __syncthreads(); }
    if (t == 0) sc[0] = sh[0];
    __syncthreads();
    sh[t] = (bl2_rev[t] + bl2_ts[t]) * Wlin[t];
    __syncthreads();
    for (int st = 64; st >= 1; st >>= 1) { if (t < st) sh[t] += sh[t + st]; __syncthreads(); }
    if (t == 0) sc[1] = sh[0];
    __syncthreads();
    float ss = 0.f;
    for (int k = t; k < 512; k += 128) { const float v = q[k]; ss = fmaf(v, v, ss); }
    sh[t] = ss;
    __syncthreads();
    for (int st = 64; st >= 1; st >>= 1) { if (t < st) sh[t] += sh[t + st]; __syncthreads(); }
    if (t == 0) sc[2] = fmaxf(sqrtf(sh[0]), 1e-12f);
}

// ---------------- A-resident multi-output MFMA GEMMs (round-13-verified) ----------------

struct B5 { const __bf16* p[5]; };
struct Y5 { __bf16* p[5]; };

__launch_bounds__(256, 2)
__global__ void gemm_col5(const float* __restrict__ X, B5 wp, const float* __restrict__ bias,
                          Y5 yp, int M) {
    __shared__ __bf16 Bs[128 * 256];   // 64 KB
    const int t = threadIdx.x;
    const int lane = t & 63;
    const int wave = t >> 6;
    const int l15 = lane & 15;
    const int kg = lane >> 4;
    const int rowbase = blockIdx.x * 128 + wave * 32;

    bf16x8 af[2][8];
#pragma unroll
    for (int m = 0; m < 2; ++m) {
        int r = rowbase + m * 16 + l15;
        r = (r < M) ? r : (M - 1);
        const float* baseA = X + (size_t)r * 256 + kg * 8;
#pragma unroll
        for (int ks = 0; ks < 8; ++ks) {
            const float4 x0 = *reinterpret_cast<const float4*>(baseA + ks * 32);
            const float4 x1 = *reinterpret_cast<const float4*>(baseA + ks * 32 + 4);
            bf16x8 tt;
            tt[0] = (__bf16)x0.x; tt[1] = (__bf16)x0.y; tt[2] = (__bf16)x0.z; tt[3] = (__bf16)x0.w;
            tt[4] = (__bf16)x1.x; tt[5] = (__bf16)x1.y; tt[6] = (__bf16)x1.z; tt[7] = (__bf16)x1.w;
            af[m][ks] = tt;
        }
    }

#pragma unroll
    for (int o = 0; o < 5; ++o) {
        __syncthreads();
        const __bf16* Wt = wp.p[o];
#pragma unroll
        for (int i = 0; i < 16; ++i) {
            const int u = t + i * 256;
            const int row = u >> 5;
            const int ku = u & 31;
            const bf16x8 v = *reinterpret_cast<const bf16x8*>(Wt + (size_t)row * 256 + ku * 8);
            *reinterpret_cast<bf16x8*>(&Bs[row * 256 + ((ku ^ (row & 7)) << 3)]) = v;
        }
        __syncthreads();
        f32x4 acc[2][8];
#pragma unroll
        for (int m = 0; m < 2; ++m)
#pragma unroll
            for (int n = 0; n < 8; ++n) acc[m][n] = (f32x4)0.f;
#pragma unroll
        for (int ks = 0; ks < 8; ++ks) {
            const int ku = ks * 4 + kg;
#pragma unroll
            for (int n = 0; n < 8; ++n) {
                const int r = n * 16 + l15;
                const bf16x8 bf = *reinterpret_cast<const bf16x8*>(&Bs[r * 256 + ((ku ^ (r & 7)) << 3)]);
                acc[0][n] = __builtin_amdgcn_mfma_f32_16x16x32_bf16(af[0][ks], bf, acc[0][n], 0, 0, 0);
                acc[1][n] = __builtin_amdgcn_mfma_f32_16x16x32_bf16(af[1][ks], bf, acc[1][n], 0, 0, 0);
            }
        }
        __bf16* Y = yp.p[o];
#pragma unroll
        for (int n = 0; n < 8; ++n) {
            const int col = n * 16 + l15;
            const float bv = (o == 0) ? bias[col] : 0.f;
#pragma unroll
            for (int m = 0; m < 2; ++m)
#pragma unroll
                for (int rr = 0; rr < 4; ++rr) {
                    const int row = rowbase + m * 16 + kg * 4 + rr;
                    if (row < M) Y[(size_t)row * 128 + col] = (__bf16)(acc[m][n][rr] + bv);
                }
        }
    }
}

struct B3 { const __bf16* p[3]; };
struct Y3 { __bf16* p[3]; };

__launch_bounds__(256, 2)
__global__ void gemm_tab3(const float* __restrict__ X, B3 wp, const float* __restrict__ bias,
                          Y3 yp, const float* __restrict__ q, const float* __restrict__ sc,
                          float* __restrict__ wgt, int M) {
    __shared__ __bf16 Bs[128 * 256];   // 64 KB (half-K chunk)
    const int t = threadIdx.x;
    const int lane = t & 63;
    const int wave = t >> 6;
    const int l15 = lane & 15;
    const int kg = lane >> 4;
    const int rowbase = blockIdx.x * 64 + wave * 16;
    const int r0 = rowbase + l15;
    const bool rv = r0 < M;
    const int rc = rv ? r0 : (M - 1);
    const float* baseA = X + (size_t)rc * 512 + kg * 8;

    bf16x8 af[16];
    float dot = 0.f, ss = 0.f;
#pragma unroll
    for (int ks = 0; ks < 16; ++ks) {
        const float4 x0 = *reinterpret_cast<const float4*>(baseA + ks * 32);
        const float4 x1 = *reinterpret_cast<const float4*>(baseA + ks * 32 + 4);
        const float4 q0 = *reinterpret_cast<const float4*>(q + kg * 8 + ks * 32);
        const float4 q1 = *reinterpret_cast<const float4*>(q + kg * 8 + ks * 32 + 4);
        dot += x0.x * q0.x + x0.y * q0.y + x0.z * q0.z + x0.w * q0.w
             + x1.x * q1.x + x1.y * q1.y + x1.z * q1.z + x1.w * q1.w;
        ss += x0.x * x0.x + x0.y * x0.y + x0.z * x0.z + x0.w * x0.w
            + x1.x * x1.x + x1.y * x1.y + x1.z * x1.z + x1.w * x1.w;
        bf16x8 tt;
        tt[0] = (__bf16)x0.x; tt[1] = (__bf16)x0.y; tt[2] = (__bf16)x0.z; tt[3] = (__bf16)x0.w;
        tt[4] = (__bf16)x1.x; tt[5] = (__bf16)x1.y; tt[6] = (__bf16)x1.z; tt[7] = (__bf16)x1.w;
        af[ks] = tt;
    }
    dot += __shfl_xor(dot, 16); dot += __shfl_xor(dot, 32);
    ss  += __shfl_xor(ss, 16);  ss  += __shfl_xor(ss, 32);
    if (lane < 16 && rv) {
        const float nx = fmaxf(sqrtf(ss), 1e-12f);
        wgt[r0] = fmaxf(dot, 0.f) / (nx * sc[2]);
    }

#pragma unroll
    for (int o = 0; o < 3; ++o) {
        f32x4 acc[8];
#pragma unroll
        for (int n = 0; n < 8; ++n) acc[n] = (f32x4)0.f;
        const __bf16* Wt = wp.p[o];
#pragma unroll
        for (int c = 0; c < 2; ++c) {
            __syncthreads();
#pragma unroll
            for (int i = 0; i < 16; ++i) {
                const int u = t + i * 256;
                const int row = u >> 5;
                const int ku = u & 31;
                const bf16x8 v = *reinterpret_cast<const bf16x8*>(Wt + (size_t)row * 512 + c * 256 + ku * 8);
                *reinterpret_cast<bf16x8*>(&Bs[row * 256 + ((ku ^ (row & 7)) << 3)]) = v;
            }
            __syncthreads();
#pragma unroll
            for (int ks = 0; ks < 8; ++ks) {
                const int ku = ks * 4 + kg;
#pragma unroll
                for (int n = 0; n < 8; ++n) {
                    const int r = n * 16 + l15;
                    const bf16x8 bf = *reinterpret_cast<const bf16x8*>(&Bs[r * 256 + ((ku ^ (r & 7)) << 3)]);
                    acc[n] = __builtin_amdgcn_mfma_f32_16x16x32_bf16(af[c * 8 + ks], bf, acc[n], 0, 0, 0);
                }
            }
        }
        __bf16* Y = yp.p[o];
#pragma unroll
        for (int n = 0; n < 8; ++n) {
            const int col = n * 16 + l15;
            const float bv = (o == 0) ? bias[col] : 0.f;
#pragma unroll
            for (int rr = 0; rr < 4; ++rr) {
                const int row = rowbase + kg * 4 + rr;
                if (row < M) Y[(size_t)row * 128 + col] = (__bf16)(acc[n][rr] + bv);
            }
        }
    }
}

// ---------------- capacity-padded CSR (count-free, windowed grid-stride fill) ----------------

struct ED { const int* dst; const int* src; int E; int ebase; int ng; int g;
            int keybase; int srcoff; int ts; };
struct ED6 { ED d[6]; };

__global__ void fill_win(ED6 ds, const float* __restrict__ ew_ts, int* __restrict__ cur,
                         int* __restrict__ ed_idx, int2* __restrict__ edT,
                         int lo, int hi, int total) {
    for (int e = blockIdx.x * blockDim.x + threadIdx.x; e < total;
         e += gridDim.x * blockDim.x) {
#pragma unroll
        for (int i = 5; i >= 0; --i) {
            if (e >= ds.d[i].ebase) {
                const ED d = ds.d[i];
                const int le = e - d.ebase;
                const int dstv = d.dst[le];
                const int key = d.keybase + dstv * d.ng + d.g;
                if (key >= lo && key < hi) {
                    const int srcv = d.src[le];
                    const int slot = atomicAdd(&cur[key], 1);
                    if (key < KB_TAB) {
                        const int g = key & 3;
                        const int cap = (g < 3) ? 32 : 16;
                        if (slot < cap)
                            ed_idx[(key >> 2) * COLSTR + g * 32 + slot] = d.srcoff + srcv;
                    } else {
                        const int k2 = key - KB_TAB;
                        if (k2 & 1) {                      // ts edge: store raw ew
                            if (slot < 72)
                                edT[(k2 >> 1) * TABSTR + 24 + slot] =
                                    make_int2(NC + srcv, __float_as_int(ew_ts[le]));
                        } else {                           // rev edge
                            if (slot < 24)
                                edT[(k2 >> 1) * TABSTR + slot] = make_int2(srcv, 0);
                        }
                    }
                }
                break;
            }
        }
    }
}

// ---------------- fused row kernels (padded-arena indexing) ----------------

__launch_bounds__(256)
__global__ void col_fused(const __bf16* __restrict__ selfRow, const __bf16* __restrict__ featCat,
                          const int* __restrict__ cur, const int* __restrict__ ed_idx,
                          const float* __restrict__ wvec, float* __restrict__ outv, int n) {
    const int wave = threadIdx.x >> 6;
    const int lane = threadIdx.x & 63;
    const int sg = lane >> 4;
    const int sl = lane & 15;
    const int row = blockIdx.x * 4 + wave;
    if (row >= n) return;
    const int4 l4 = *reinterpret_cast<const int4*>(&cur[row * 4]);
    int len[4];
    len[0] = (l4.x < 32) ? l4.x : 32;
    len[1] = (l4.y < 32) ? l4.y : 32;
    len[2] = (l4.z < 32) ? l4.z : 32;
    len[3] = (l4.w < 16) ? l4.w : 16;
    const int rowbase = row * COLSTR;
    float s8[8] = {0.f, 0.f, 0.f, 0.f, 0.f, 0.f, 0.f, 0.f};
#pragma unroll
    for (int g = 0; g < 4; ++g) {
        const int lg = len[g];
        if (lg <= 0) continue;
        const int base = rowbase + g * 32;
        const float w = 1.0f / (float)lg;
        int j = sg;
        for (; j + 4 < lg; j += 8) {
            const int s0 = ed_idx[base + j];
            const int s1 = ed_idx[base + j + 4];
            const bf16x8 v0 = *reinterpret_cast<const bf16x8*>(&featCat[(size_t)s0 * 128 + sl * 8]);
            const bf16x8 v1 = *reinterpret_cast<const bf16x8*>(&featCat[(size_t)s1 * 128 + sl * 8]);
#pragma unroll
            for (int t = 0; t < 8; ++t) {
                s8[t] = fmaf(w, (float)v0[t], s8[t]);
                s8[t] = fmaf(w, (float)v1[t], s8[t]);
            }
        }
        if (j < lg) {
            const int s0 = ed_idx[base + j];
            const bf16x8 v0 = *reinterpret_cast<const bf16x8*>(&featCat[(size_t)s0 * 128 + sl * 8]);
#pragma unroll
            for (int t = 0; t < 8; ++t) s8[t] = fmaf(w, (float)v0[t], s8[t]);
        }
    }
#pragma unroll
    for (int t = 0; t < 8; ++t) {
        s8[t] += __shfl_xor(s8[t], 16);
        s8[t] += __shfl_xor(s8[t], 32);
    }
    const bf16x8 gv = *reinterpret_cast<const bf16x8*>(&selfRow[(size_t)row * 128 + sl * 8]);
    const float4 w0 = *reinterpret_cast<const float4*>(&wvec[sl * 8]);
    const float4 w1 = *reinterpret_cast<const float4*>(&wvec[sl * 8 + 4]);
    const float ww[8] = {w0.x, w0.y, w0.z, w0.w, w1.x, w1.y, w1.z, w1.w};
    float d = 0.f;
#pragma unroll
    for (int t = 0; t < 8; ++t) d = fmaf(fmaxf(s8[t] + (float)gv[t], 0.f), ww[t], d);
#pragma unroll
    for (int off = 8; off; off >>= 1) d += __shfl_xor(d, off);
    if (lane == 0) outv[row] = d;
}

__launch_bounds__(256)
__global__ void tab_fused(const __bf16* __restrict__ selfRow, const __bf16* __restrict__ featCat,
                          const int* __restrict__ cur, const int2* __restrict__ edT,
                          const float* __restrict__ wa, const float* __restrict__ wb,
                          float* __restrict__ ya, float* __restrict__ yb, int n) {
    const int wave = threadIdx.x >> 6;
    const int lane = threadIdx.x & 63;
    const int sg = lane >> 4;
    const int sl = lane & 15;
    const int row = blockIdx.x * 4 + wave;
    if (row >= n) return;
    const int2 l2 = *reinterpret_cast<const int2*>(&cur[KB_TAB + row * 2]);
    int len[2];
    len[0] = (l2.x < 24) ? l2.x : 24;
    len[1] = (l2.y < 72) ? l2.y : 72;
    const int rowbase = row * TABSTR;
    float s8[8] = {0.f, 0.f, 0.f, 0.f, 0.f, 0.f, 0.f, 0.f};
#pragma unroll
    for (int g = 0; g < 2; ++g) {
        const int lg = len[g];
        if (lg <= 0) continue;
        const int base = rowbase + g * 24;
        const float w = 1.0f / (float)lg;
        int j = sg;
        for (; j + 4 < lg; j += 8) {
            const int s0 = edT[base + j].x;
            const int s1 = edT[base + j + 4].x;
            const bf16x8 v0 = *reinterpret_cast<const bf16x8*>(&featCat[(size_t)s0 * 128 + sl * 8]);
            const bf16x8 v1 = *reinterpret_cast<const bf16x8*>(&featCat[(size_t)s1 * 128 + sl * 8]);
#pragma unroll
            for (int t = 0; t < 8; ++t) {
                s8[t] = fmaf(w, (float)v0[t], s8[t]);
                s8[t] = fmaf(w, (float)v1[t], s8[t]);
            }
        }
        if (j < lg) {
            const int s0 = edT[base + j].x;
            const bf16x8 v0 = *reinterpret_cast<const bf16x8*>(&featCat[(size_t)s0 * 128 + sl * 8]);
#pragma unroll
            for (int t = 0; t < 8; ++t) s8[t] = fmaf(w, (float)v0[t], s8[t]);
        }
    }
#pragma unroll
    for (int t = 0; t < 8; ++t) {
        s8[t] += __shfl_xor(s8[t], 16);
        s8[t] += __shfl_xor(s8[t], 32);
    }
    const bf16x8 gv = *reinterpret_cast<const bf16x8*>(&selfRow[(size_t)row * 128 + sl * 8]);
    const float4 a0 = *reinterpret_cast<const float4*>(&wa[sl * 8]);
    const float4 a1 = *reinterpret_cast<const float4*>(&wa[sl * 8 + 4]);
    const float4 b0 = *reinterpret_cast<const float4*>(&wb[sl * 8]);
    const float4 b1 = *reinterpret_cast<const float4*>(&wb[sl * 8 + 4]);
    const float wwa[8] = {a0.x, a0.y, a0.z, a0.w, a1.x, a1.y, a1.z, a1.w};
    const float wwb[8] = {b0.x, b0.y, b0.z, b0.w, b1.x, b1.y, b1.z, b1.w};
    float da = 0.f, db = 0.f;
#pragma unroll
    for (int t = 0; t < 8; ++t) {
        const float rv = fmaxf(s8[t] + (float)gv[t], 0.f);
        da = fmaf(rv, wwa[t], da);
        db = fmaf(rv, wwb[t], db);
    }
#pragma unroll
    for (int off = 8; off; off >>= 1) { da += __shfl_xor(da, off); db += __shfl_xor(db, off); }
    if (lane == 0) { ya[row] = da; yb[row] = db; }
}

// ---------------- discrete tail (deg-free) ----------------

// per-row: dis from sequential ts ew sum (+self-loop 1) and y0 from arena means
__launch_bounds__(256)
__global__ void tail_pre(const int* __restrict__ cur, const int2* __restrict__ edT,
                         const float* __restrict__ tvs, const float* __restrict__ val2,
                         const float* __restrict__ wgt, const float* __restrict__ sc,
                         float* __restrict__ dis, float* __restrict__ y0, int n) {
    const int row = blockIdx.x * 16 + (threadIdx.x >> 4);
    const int l = threadIdx.x & 15;
    if (row >= n) return;
    const int2 l2 = *reinterpret_cast<const int2*>(&cur[KB_TAB + row * 2]);
    const int lenR = (l2.x < 24) ? l2.x : 24;
    const int lenT = (l2.y < 72) ? l2.y : 72;
    const int baseR = row * TABSTR;
    const int baseT = baseR + 24;
    float sdeg = 0.f, sy = 0.f;
    const float wR = (lenR > 0) ? 1.0f / (float)lenR : 0.f;
    for (int j = l; j < lenR; j += 16) sy = fmaf(wR, val2[edT[baseR + j].x], sy);
    const float wT = (lenT > 0) ? 1.0f / (float)lenT : 0.f;
    for (int j = l; j < lenT; j += 16) {
        const int2 p = edT[baseT + j];
        sdeg += __int_as_float(p.y);
        sy = fmaf(wT, val2[p.x], sy);
    }
#pragma unroll
    for (int off = 8; off; off >>= 1) {
        sdeg += __shfl_xor(sdeg, off);
        sy += __shfl_xor(sy, off);
    }
    if (l == 0) {
        const float dg = sdeg + 1.0f;
        dis[row] = (dg > 0.f) ? (1.0f / sqrtf(dg)) : 0.f;
        y0[row] = tvs[row] + sc[1] + wgt[row] * sc[0] + sy;
    }
}

// bake nrm = dis[src]*ew*dis[dst] into ts slots
__launch_bounds__(256)
__global__ void nrm_bake(int2* __restrict__ edT, const int* __restrict__ cur,
                         const float* __restrict__ dis, int n) {
    const int row = blockIdx.x * 16 + (threadIdx.x >> 4);
    const int l = threadIdx.x & 15;
    if (row >= n) return;
    int lenT = cur[KB_TAB + row * 2 + 1];
    lenT = (lenT < 72) ? lenT : 72;
    const int baseT = row * TABSTR + 24;
    const float dr = dis[row];
    for (int j = l; j < lenT; j += 16) {
        const int2 p = edT[baseT + j];
        edT[baseT + j].y = __float_as_int(dis[p.x - NC] * __int_as_float(p.y) * dr);
    }
}

// scalar APPNP step; int2 {NC+src, nrm} ts arena; fused final output
__launch_bounds__(256)
__global__ void appnp_s(const float* __restrict__ z, const float* __restrict__ y0,
                        const int* __restrict__ cur, const int2* __restrict__ edT,
                        const float* __restrict__ dis, float* __restrict__ zo,
                        const float* __restrict__ blin, float* __restrict__ out,
                        int n, int last) {
    const int row = blockIdx.x * 16 + (threadIdx.x >> 4);
    const int l = threadIdx.x & 15;
    if (row >= n) return;
    int lg = cur[KB_TAB + row * 2 + 1];
    lg = (lg < 72) ? lg : 72;
    const int base = row * TABSTR + 24;
    float s = 0.f;
    int j = l;
    for (; j + 16 < lg; j += 32) {
        const int2 p0 = edT[base + j];
        const int2 p1 = edT[base + j + 16];
        s = fmaf(__int_as_float(p0.y), z[p0.x - NC], s);
        s = fmaf(__int_as_float(p1.y), z[p1.x - NC], s);
    }
    if (j < lg) {
        const int2 p0 = edT[base + j];
        s = fmaf(__int_as_float(p0.y), z[p0.x - NC], s);
    }
#pragma unroll
    for (int off = 8; off; off >>= 1) s += __shfl_xor(s, off);
    if (l == 0) {
        const float d = dis[row];
        const float v = 0.8f * (s + d * d * z[row]) + 0.2f * y0[row];
        if (last) out[row] = v + blin[0];
        else zo[row] = v;
    }
}

// ---------------- host ----------------

extern "C" void kernel_launch(void* const* d_in, const int* in_sizes, int n_in,
                              void* d_out, int out_size, void* d_ws, size_t ws_size,
                              hipStream_t stream) {
    const float* table_x  = (const float*)d_in[0];
    const float* column_x = (const float*)d_in[1];
    const float* q        = (const float*)d_in[2];
    const float* Wl1_tc  = (const float*)d_in[3];  const float* bl1_tc  = (const float*)d_in[4];  const float* Wr1_tc  = (const float*)d_in[5];
    const float* Wl1_rev = (const float*)d_in[6];  const float* bl1_rev = (const float*)d_in[7];  const float* Wr1_rev = (const float*)d_in[8];
    const float* Wl1_cs  = (const float*)d_in[9];  const float* bl1_cs  = (const float*)d_in[10]; const float* Wr1_cs  = (const float*)d_in[11];
    const float* Wl1_ns  = (const float*)d_in[12]; const float* bl1_ns  = (const float*)d_in[13]; const float* Wr1_ns  = (const float*)d_in[14];
    const float* Wl1_ds  = (const float*)d_in[15]; const float* bl1_ds  = (const float*)d_in[16]; const float* Wr1_ds  = (const float*)d_in[17];
    const float* Wl1_ts  = (const float*)d_in[18]; const float* bl1_ts  = (const float*)d_in[19]; const float* Wr1_ts  = (const float*)d_in[20];
    const float* Wl2_rev = (const float*)d_in[21]; const float* bl2_rev = (const float*)d_in[22]; const float* Wr2_rev = (const float*)d_in[23];
    const float* Wl2_ts  = (const float*)d_in[24]; const float* bl2_ts  = (const float*)d_in[25]; const float* Wr2_ts  = (const float*)d_in[26];
    const float* Wq   = (const float*)d_in[27]; const float* bq   = (const float*)d_in[28];
    const float* Wlin = (const float*)d_in[29]; const float* blin = (const float*)d_in[30];
    const float* ts_ew = (const float*)d_in[31];
    const int* tc_src = (const int*)d_in[32];
    const int* tc_dst = (const int*)d_in[33];
    const int* cs_ei  = (const int*)d_in[34];
    const int* ns_ei  = (const int*)d_in[35];
    const int* ds_ei  = (const int*)d_in[36];
    const int* ts_ei  = (const int*)d_in[37];

    // ---- workspace carve ----
    char* w = (char*)d_ws;
    size_t off = 0;
    auto alloc = [&](size_t bytes) -> void* {
        void* p = w + off;
        off += (bytes + 255) & ~(size_t)255;
        return p;
    };
    __bf16* featC = (__bf16*)alloc(((size_t)3 * NC + NT) * 128 * 2);  // cs | ns | ds | tc
    __bf16* featT = (__bf16*)alloc(((size_t)NC + NT) * 128 * 2);      // rev | ts
    __bf16* projC_cs  = featC;
    __bf16* projC_ns  = featC + (size_t)NC * 128;
    __bf16* projC_ds  = featC + (size_t)2 * NC * 128;
    __bf16* projT_tc  = featC + (size_t)3 * NC * 128;
    __bf16* projC_rev = featT;
    __bf16* projT_ts  = featT + (size_t)NC * 128;
    __bf16* gemmC = (__bf16*)alloc((size_t)NC * 128 * 2);
    __bf16* gemmT = (__bf16*)alloc((size_t)NT * 128 * 2);
    float* val2  = (float*)alloc((size_t)(NC + NT) * 4);   // colv | tvt
    float* f_colv = val2;
    float* f_tvt  = val2 + NC;
    float* f_tvs = (float*)alloc((size_t)NT * 4);
    float* f_wgt = (float*)alloc((size_t)NT * 4);
    float* f_dis = (float*)alloc((size_t)NT * 4);
    float* f_y0  = (float*)alloc((size_t)NT * 4);
    float* f_za  = (float*)alloc((size_t)NT * 4);
    float* f_zb  = (float*)alloc((size_t)NT * 4);
    __bf16* WtS1c  = (__bf16*)alloc((size_t)128 * 256 * 2);
    __bf16* Wt_cs  = (__bf16*)alloc((size_t)128 * 256 * 2);
    __bf16* Wt_ns  = (__bf16*)alloc((size_t)128 * 256 * 2);
    __bf16* Wt_ds  = (__bf16*)alloc((size_t)128 * 256 * 2);
    __bf16* Wt_rev = (__bf16*)alloc((size_t)128 * 256 * 2);
    __bf16* Wt_tc  = (__bf16*)alloc((size_t)128 * 512 * 2);
    __bf16* WtS1t  = (__bf16*)alloc((size_t)128 * 512 * 2);
    __bf16* Wt_ts  = (__bf16*)alloc((size_t)128 * 512 * 2);
    float* f_biasC  = (float*)alloc(128 * 4);
    float* f_biasT1 = (float*)alloc(128 * 4);
    float* f_w2s  = (float*)alloc(128 * 4);
    float* f_wrev = (float*)alloc(128 * 4);
    float* f_wts  = (float*)alloc(128 * 4);
    float* f_sc   = (float*)alloc(16 * 4);
    int* i_cur  = (int*)alloc((size_t)NKEY * 4);
    int* ed_idx = (int*)alloc((size_t)NC * COLSTR * 4);    // padded col arena
    int2* edT   = (int2*)alloc((size_t)NT * TABSTR * 8);   // padded tab arena
    if (off > ws_size) return;

    auto cdiv = [](int a, int b) { return (a + b - 1) / b; };

    // ---- weight/vector prep (2 dispatches) ----
    {
        WD8 ds;
        int eb = 0;
        auto set = [&](int i, const float* a, const float* b2, const float* c, const float* d2,
                       __bf16* o, int K, int ksh) {
            ds.d[i] = {a, b2, c, d2, o, K, ksh, eb};
            eb += 128 * K;
        };
        set(0, Wr1_tc, Wr1_cs, Wr1_ns, Wr1_ds, WtS1c, 256, 8);
        set(1, Wl1_cs, nullptr, nullptr, nullptr, Wt_cs, 256, 8);
        set(2, Wl1_ns, nullptr, nullptr, nullptr, Wt_ns, 256, 8);
        set(3, Wl1_ds, nullptr, nullptr, nullptr, Wt_ds, 256, 8);
        set(4, Wl1_rev, nullptr, nullptr, nullptr, Wt_rev, 256, 8);
        set(5, Wl1_tc, nullptr, nullptr, nullptr, Wt_tc, 512, 9);
        set(6, Wr1_rev, Wr1_ts, nullptr, nullptr, WtS1t, 512, 9);
        set(7, Wl1_ts, nullptr, nullptr, nullptr, Wt_ts, 512, 9);
        wprep_all<<<cdiv(eb, 256), 256, 0, stream>>>(ds, eb);
    }
    vecprep<<<1, 128, 0, stream>>>(q, Wq, bq, Wr2_rev, Wr2_ts, Wl2_rev, Wl2_ts,
                                   bl2_rev, bl2_ts, Wlin, bl1_tc, bl1_cs, bl1_ns, bl1_ds,
                                   bl1_rev, bl1_ts, f_biasC, f_biasT1,
                                   f_w2s, f_wrev, f_wts, f_sc);

    // ---- GEMMs: A-resident, X read once per side ----
    {
        B5 wp; wp.p[0] = WtS1c; wp.p[1] = Wt_cs; wp.p[2] = Wt_ns; wp.p[3] = Wt_ds; wp.p[4] = Wt_rev;
        Y5 yp; yp.p[0] = gemmC; yp.p[1] = projC_cs; yp.p[2] = projC_ns; yp.p[3] = projC_ds; yp.p[4] = projC_rev;
        gemm_col5<<<cdiv(NC, 128), 256, 0, stream>>>(column_x, wp, f_biasC, yp, NC);
    }
    {
        B3 wp; wp.p[0] = WtS1t; wp.p[1] = Wt_tc; wp.p[2] = Wt_ts;
        Y3 yp; yp.p[0] = gemmT; yp.p[1] = projT_tc; yp.p[2] = projT_ts;
        gemm_tab3<<<cdiv(NT, 64), 256, 0, stream>>>(table_x, wp, f_biasT1, yp, q, f_sc, f_wgt, NT);
    }

    // ---- count-free padded CSR: windowed grid-stride fills ----
    ED6 cds;
    cds.d[0] = {cs_ei + E_SIM, cs_ei, E_SIM, 0,                  4, 0, KB_COL, 0,      0};
    cds.d[1] = {ns_ei + E_SIM, ns_ei, E_SIM, E_SIM,              4, 1, KB_COL, NC,     0};
    cds.d[2] = {ds_ei + E_SIM, ds_ei, E_SIM, 2 * E_SIM,          4, 2, KB_COL, 2 * NC, 0};
    cds.d[3] = {tc_dst, tc_src, E_TC, 3 * E_SIM,                 4, 3, KB_COL, 3 * NC, 0};
    cds.d[4] = {tc_src, tc_dst, E_TC, 3 * E_SIM + E_TC,          2, 0, KB_TAB, 0,      0};
    cds.d[5] = {ts_ei + E_TS, ts_ei, E_TS, 3 * E_SIM + 2 * E_TC, 2, 1, KB_TAB, NC,     1};

    hipMemsetAsync(i_cur, 0, (size_t)NKEY * 4, stream);
    for (int p = 0; p < NPASS; ++p) {
        const int lo = (int)((long long)NKEY * p / NPASS);
        const int hi = (int)((long long)NKEY * (p + 1) / NPASS);
        fill_win<<<GFILL, 256, 0, stream>>>(cds, ts_ew, i_cur, ed_idx, edT, lo, hi, NED_AB);
    }

    // ---- fused aggregation + relu + dot ----
    col_fused<<<cdiv(NC, 4), 256, 0, stream>>>(gemmC, featC, i_cur, ed_idx,
                                               f_wrev, f_colv, NC);
    tab_fused<<<cdiv(NT, 4), 256, 0, stream>>>(gemmT, featT, i_cur, edT,
                                               f_w2s, f_wts, f_tvs, f_tvt, NT);

    // ---- discrete tail: dis+y0 -> nrm bake -> 10x APPNP -> out ----
    tail_pre<<<cdiv(NT, 16), 256, 0, stream>>>(i_cur, edT, f_tvs, val2, f_wgt, f_sc,
                                               f_dis, f_y0, NT);
    nrm_bake<<<cdiv(NT, 16), 256, 0, stream>>>(edT, i_cur, f_dis, NT);

    const float* zin = f_y0;
    float* zout = f_za;
    for (int it = 0; it < 10; ++it) {
        const int last = (it == 9);
        appnp_s<<<cdiv(NT, 16), 256, 0, stream>>>(zin, f_y0, i_cur, edT,
                                                  f_dis, zout, blin, (float*)d_out, NT, last);
        zin = zout;
        zout = (zout == f_za) ? f_zb : f_za;
    }
}